// Round 1
// baseline (221.468 us; speedup 1.0000x reference)
//
#include <hip/hip_runtime.h>
#include <math.h>

// PAM module: B=8, C=64, CQ=8, N=H*W*D=2048
// out[b,c,i] = gamma * sum_j softmax_j(q[b,i,:]·k[b,:,j]) * v[b,c,j] + x[b,c,i]

#define NB  8
#define NC  64
#define NCQ 8
#define NN  2048
#define JT  128          // j-tile width
#define RI  32           // rows (queries) per workgroup
#define PITCH_P 132      // padded pitch for P tile (dwords)

typedef float float4_ __attribute__((ext_vector_type(4)));

// ---------------- QKV projection ----------------
// one thread per (b, n); weights transposed in LDS for float4 reads
__global__ __launch_bounds__(256) void qkv_kernel(
    const float* __restrict__ x,
    const float* __restrict__ Wq, const float* __restrict__ bq,
    const float* __restrict__ Wk, const float* __restrict__ bk,
    const float* __restrict__ Wv, const float* __restrict__ bv,
    float* __restrict__ Qws, float* __restrict__ Kws, float* __restrict__ Vws)
{
    __shared__ float sWqT[NC*NCQ], sWkT[NC*NCQ], sWvT[NC*NC];
    __shared__ float sbq[NCQ], sbk[NCQ], sbv[NC];
    const int tid = threadIdx.x;

    for (int idx = tid; idx < NC*NCQ; idx += 256) {
        int c = idx >> 3, o = idx & 7;
        sWqT[idx] = Wq[o*NC + c];
        sWkT[idx] = Wk[o*NC + c];
    }
    for (int idx = tid; idx < NC*NC; idx += 256) {
        int c = idx >> 6, o = idx & 63;
        sWvT[idx] = Wv[o*NC + c];
    }
    if (tid < NCQ) { sbq[tid] = bq[tid]; sbk[tid] = bk[tid]; }
    if (tid < NC)  sbv[tid] = bv[tid];
    __syncthreads();

    const int gid = blockIdx.x * 256 + tid;
    const int b = gid >> 11;          // / NN
    const int n = gid & (NN - 1);

    // preload the 64 strided x values (coalesced across lanes)
    const float* xb = x + (size_t)b * NC * NN + n;
    float xr[NC];
    #pragma unroll
    for (int c = 0; c < NC; c++) xr[c] = xb[(size_t)c * NN];

    float q[NCQ], k[NCQ], v[NC];
    #pragma unroll
    for (int o = 0; o < NCQ; o++) { q[o] = sbq[o]; k[o] = sbk[o]; }
    #pragma unroll
    for (int o = 0; o < NC; o++) v[o] = sbv[o];

    for (int c = 0; c < NC; c++) {
        const float xv = xr[c];
        const float4_* wq4 = (const float4_*)&sWqT[c*NCQ];
        const float4_* wk4 = (const float4_*)&sWkT[c*NCQ];
        const float4_* wv4 = (const float4_*)&sWvT[c*NC];
        #pragma unroll
        for (int o4 = 0; o4 < NCQ/4; o4++) {
            float4_ wa = wq4[o4], wb = wk4[o4];
            #pragma unroll
            for (int e = 0; e < 4; e++) {
                q[o4*4+e] = fmaf(wa[e], xv, q[o4*4+e]);
                k[o4*4+e] = fmaf(wb[e], xv, k[o4*4+e]);
            }
        }
        #pragma unroll
        for (int o4 = 0; o4 < NC/4; o4++) {
            float4_ w = wv4[o4];
            #pragma unroll
            for (int e = 0; e < 4; e++)
                v[o4*4+e] = fmaf(w[e], xv, v[o4*4+e]);
        }
    }

    // Q: [B][N][CQ] (row-contiguous, float4-aligned)
    float* qo = Qws + ((size_t)b * NN + n) * NCQ;
    float4_ q0 = { q[0], q[1], q[2], q[3] };
    float4_ q1 = { q[4], q[5], q[6], q[7] };
    *(float4_*)qo       = q0;
    *(float4_*)(qo + 4) = q1;
    // K: [B][CQ][N]
    #pragma unroll
    for (int o = 0; o < NCQ; o++)
        Kws[((size_t)b * NCQ + o) * NN + n] = k[o];
    // V: [B][C][N]
    #pragma unroll
    for (int o = 0; o < NC; o++)
        Vws[((size_t)b * NC + o) * NN + n] = v[o];
}

// ---------------- fused flash attention + gamma*out + x ----------------
// block = 256 threads = 32 rows x 8 lane-groups; each thread owns 8 output
// channels (c = s*8 + cc) for its row, with online softmax state per row.
__global__ __launch_bounds__(256) void attn_kernel(
    const float* __restrict__ Qws, const float* __restrict__ Kws,
    const float* __restrict__ Vws, const float* __restrict__ x,
    const float* __restrict__ gamma, float* __restrict__ out)
{
    __shared__ float sK[NCQ][JT];        // 4 KB
    __shared__ float sV[NC * JT];        // 32 KB, XOR-swizzled in float4 units
    __shared__ float sP[RI][PITCH_P];    // 16.9 KB

    const int tid = threadIdx.x;
    const int r = tid >> 3;              // row in block: 0..31
    const int s = tid & 7;               // lane-group:   0..7
    const int blk = blockIdx.x;
    const int b = blk >> 6;              // 64 row-blocks per batch
    const int i = ((blk & 63) * RI) + r; // global query row

    // per-row query (redundant across the 8 s-lanes, tiny)
    const float* qp = Qws + ((size_t)b * NN + i) * NCQ;
    float4_ qa = *(const float4_*)qp;
    float4_ qb = *(const float4_*)(qp + 4);
    float q[NCQ] = { qa[0], qa[1], qa[2], qa[3], qb[0], qb[1], qb[2], qb[3] };

    float m = -INFINITY;
    float l = 0.f;
    float acc[8];
    #pragma unroll
    for (int cc = 0; cc < 8; cc++) acc[cc] = 0.f;

    const float* Kb = Kws + (size_t)b * NCQ * NN;
    const float* Vb = Vws + (size_t)b * NC * NN;

    for (int j0 = 0; j0 < NN; j0 += JT) {
        __syncthreads();   // previous tile's LDS fully consumed
        // ---- K tile: [CQ][JT], linear ----
        for (int idx = tid; idx < NCQ*JT; idx += 256) {
            int o = idx >> 7, jj = idx & (JT-1);
            sK[o][jj] = Kb[(size_t)o * NN + j0 + jj];
        }
        // ---- V tile: float4 units, XOR swizzle by (c>>3) so that the
        //      8 s-lanes (c = s*8+cc) read distinct bank quads ----
        for (int idx = tid; idx < NC*(JT/4); idx += 256) {
            int c = idx >> 5, jj4 = idx & 31;
            float4_ vv = *(const float4_*)(Vb + (size_t)c * NN + j0 + (jj4 << 2));
            int f4 = (c << 5) | (jj4 ^ ((c >> 3) & 7));
            *(float4_*)&sV[f4 << 2] = vv;
        }
        __syncthreads();

        // ---- energies: thread handles jj = u*8 + s (conflict-free sK reads) ----
        float e[16];
        float emax = -INFINITY;
        #pragma unroll
        for (int u = 0; u < 16; u++) {
            const int jj = (u << 3) + s;
            float sum = 0.f;
            #pragma unroll
            for (int o = 0; o < NCQ; o++) sum = fmaf(q[o], sK[o][jj], sum);
            e[u] = sum;
            emax = fmaxf(emax, sum);
        }
        // row max across the 8 s-lanes (same wave)
        emax = fmaxf(emax, __shfl_xor(emax, 1));
        emax = fmaxf(emax, __shfl_xor(emax, 2));
        emax = fmaxf(emax, __shfl_xor(emax, 4));

        const float newm = fmaxf(m, emax);
        const float scale = __expf(m - newm);   // 0 on first tile (m=-inf)
        m = newm;
        l *= scale;
        #pragma unroll
        for (int cc = 0; cc < 8; cc++) acc[cc] *= scale;

        float lsum = 0.f;
        #pragma unroll
        for (int u = 0; u < 16; u++) {
            float p = __expf(e[u] - m);
            lsum += p;
            sP[r][(u << 3) + s] = p;   // row written entirely by this wave
        }
        l += lsum;
        // no barrier needed: sP row produced & consumed by the same wave

        // ---- PV: acc[cc] += sum_j P[r][j] * V[s*8+cc][j] ----
        #pragma unroll 4
        for (int jj4 = 0; jj4 < JT/4; jj4++) {
            const float4_ p4 = *(const float4_*)&sP[r][jj4 << 2];
            #pragma unroll
            for (int cc = 0; cc < 8; cc++) {
                const int c = (s << 3) | cc;
                const int f4 = (c << 5) | (jj4 ^ s);   // (c>>3)&7 == s
                const float4_ v4 = *(const float4_*)&sV[f4 << 2];
                acc[cc] = fmaf(p4[0], v4[0], acc[cc]);
                acc[cc] = fmaf(p4[1], v4[1], acc[cc]);
                acc[cc] = fmaf(p4[2], v4[2], acc[cc]);
                acc[cc] = fmaf(p4[3], v4[3], acc[cc]);
            }
        }
    }

    // total denominator across the row's 8 lanes
    float ltot = l;
    ltot += __shfl_xor(ltot, 1);
    ltot += __shfl_xor(ltot, 2);
    ltot += __shfl_xor(ltot, 4);
    const float inv_l = 1.0f / ltot;
    const float g = gamma[0];

    const size_t base = (size_t)b * NC * NN + i;
    #pragma unroll
    for (int cc = 0; cc < 8; cc++) {
        const int c = (s << 3) | cc;
        const size_t idx = base + (size_t)c * NN;
        out[idx] = fmaf(g, acc[cc] * inv_l, x[idx]);
    }
}

extern "C" void kernel_launch(void* const* d_in, const int* in_sizes, int n_in,
                              void* d_out, int out_size, void* d_ws, size_t ws_size,
                              hipStream_t stream) {
    const float* x     = (const float*)d_in[0];
    const float* Wq    = (const float*)d_in[1];
    const float* bq    = (const float*)d_in[2];
    const float* Wk    = (const float*)d_in[3];
    const float* bk    = (const float*)d_in[4];
    const float* Wv    = (const float*)d_in[5];
    const float* bv    = (const float*)d_in[6];
    const float* gamma = (const float*)d_in[7];
    float* out = (float*)d_out;

    // workspace layout (floats): Q[8][2048][8], K[8][8][2048], V[8][64][2048] ~ 5 MB
    float* Qws = (float*)d_ws;
    float* Kws = Qws + (size_t)NB * NN * NCQ;   // +131072
    float* Vws = Kws + (size_t)NB * NCQ * NN;   // +131072

    qkv_kernel<<<(NB * NN) / 256, 256, 0, stream>>>(
        x, Wq, bq, Wk, bk, Wv, bv, Qws, Kws, Vws);
    attn_kernel<<<NB * (NN / RI), 256, 0, stream>>>(
        Qws, Kws, Vws, x, gamma, out);
}

// Round 2
// 59.794 us; speedup vs baseline: 3.7038x; 3.7038x over previous
//
#include <hip/hip_runtime.h>
#include <math.h>

// PAM module: B=8, C=64, CQ=8, N=2048
// out[b,c,i] = gamma * sum_j softmax_j(q[i,:]·k[:,j]) * v[c,j] + x[b,c,i]

#define NB  8
#define NC  64
#define NCQ 8
#define NN  2048
#define JT  128
#define NT  (NN / JT)       // 16 j-tiles
#define PITCH 136           // ushorts per row of V/P LDS tiles (JT + 8 pad)

typedef float f32x4 __attribute__((ext_vector_type(4)));
typedef __bf16 bf16x8 __attribute__((ext_vector_type(8)));
typedef unsigned short ushort_t;

__device__ __forceinline__ unsigned short f2bf(float f) {
    unsigned u = __float_as_uint(f);
    u += 0x7fffu + ((u >> 16) & 1u);          // RNE
    return (unsigned short)(u >> 16);
}
__device__ __forceinline__ float bf2f(unsigned short h) {
    return __uint_as_float(((unsigned)h) << 16);
}

// ---------------- QKV projection ----------------
// one thread per (b,n); 64-thread blocks so all 256 CUs get work.
// Q,K written as [B][N][16] bf16 rows = [hi(8) | lo(8)] (double-bf16 split).
// V written as [B][C][N] bf16.
__global__ __launch_bounds__(64) void qkv_kernel(
    const float* __restrict__ x,
    const float* __restrict__ Wq, const float* __restrict__ bq,
    const float* __restrict__ Wk, const float* __restrict__ bk,
    const float* __restrict__ Wv, const float* __restrict__ bv,
    ushort_t* __restrict__ Qws, ushort_t* __restrict__ Kws,
    ushort_t* __restrict__ Vws)
{
    __shared__ float sWqT[NC*NCQ], sWkT[NC*NCQ], sWvT[NC*NC];
    __shared__ float sbq[NCQ], sbk[NCQ], sbv[NC];
    const int tid = threadIdx.x;

    for (int idx = tid; idx < NC*NCQ; idx += 64) {
        int c = idx >> 3, o = idx & 7;
        sWqT[idx] = Wq[o*NC + c];
        sWkT[idx] = Wk[o*NC + c];
    }
    for (int idx = tid; idx < NC*NC; idx += 64) {
        int c = idx >> 6, o = idx & 63;
        sWvT[idx] = Wv[o*NC + c];
    }
    if (tid < NCQ) { sbq[tid] = bq[tid]; sbk[tid] = bk[tid]; }
    sbv[tid] = bv[tid];
    __syncthreads();

    const int gid = blockIdx.x * 64 + tid;
    const int b = gid >> 11;
    const int n = gid & (NN - 1);

    const float* xb = x + (size_t)b * NC * NN + n;
    float xr[NC];
    #pragma unroll
    for (int c = 0; c < NC; c++) xr[c] = xb[(size_t)c * NN];

    float q[NCQ], k[NCQ], v[NC];
    #pragma unroll
    for (int o = 0; o < NCQ; o++) { q[o] = sbq[o]; k[o] = sbk[o]; }
    #pragma unroll
    for (int o = 0; o < NC; o++) v[o] = sbv[o];

    for (int c = 0; c < NC; c++) {
        const float xv = xr[c];
        const f32x4* wq4 = (const f32x4*)&sWqT[c*NCQ];
        const f32x4* wk4 = (const f32x4*)&sWkT[c*NCQ];
        const f32x4* wv4 = (const f32x4*)&sWvT[c*NC];
        #pragma unroll
        for (int o4 = 0; o4 < NCQ/4; o4++) {
            f32x4 wa = wq4[o4], wb = wk4[o4];
            #pragma unroll
            for (int e = 0; e < 4; e++) {
                q[o4*4+e] = fmaf(wa[e], xv, q[o4*4+e]);
                k[o4*4+e] = fmaf(wb[e], xv, k[o4*4+e]);
            }
        }
        #pragma unroll
        for (int o4 = 0; o4 < NC/4; o4++) {
            f32x4 w = wv4[o4];
            #pragma unroll
            for (int e = 0; e < 4; e++)
                v[o4*4+e] = fmaf(w[e], xv, v[o4*4+e]);
        }
    }

    // Q row: [hi(8) | lo(8)]
    ushort_t qrow[16], krow[16];
    #pragma unroll
    for (int o = 0; o < NCQ; o++) {
        unsigned short qh = f2bf(q[o]);
        qrow[o] = qh; qrow[8+o] = f2bf(q[o] - bf2f(qh));
        unsigned short kh = f2bf(k[o]);
        krow[o] = kh; krow[8+o] = f2bf(k[o] - bf2f(kh));
    }
    ushort_t* qo = Qws + ((size_t)b * NN + n) * 16;
    ushort_t* ko = Kws + ((size_t)b * NN + n) * 16;
    #pragma unroll
    for (int h = 0; h < 2; h++) {
        bf16x8 qv = *(const bf16x8*)&qrow[h*8];
        bf16x8 kv = *(const bf16x8*)&krow[h*8];
        *(bf16x8*)(qo + h*8) = qv;
        *(bf16x8*)(ko + h*8) = kv;
    }
    #pragma unroll
    for (int c = 0; c < NC; c++)
        Vws[((size_t)b * NC + c) * NN + n] = f2bf(v[c]);
}

// ---------------- fused flash attention (MFMA) ----------------
// 128 threads = 2 waves x 16 query rows. grid = 8 * 64 = 512 blocks.
// Swapped-operand MFMAs keep the query index in lane&15 throughout.
__global__ __launch_bounds__(128) void attn_kernel(
    const ushort_t* __restrict__ Qg, const ushort_t* __restrict__ Kg,
    const ushort_t* __restrict__ Vg, const float* __restrict__ x,
    const float* __restrict__ gamma, float* __restrict__ out)
{
    __shared__ __align__(16) ushort_t sK[2][JT][16];     // 8 KB  (dbuf)
    __shared__ __align__(16) ushort_t sV[2][NC][PITCH];  // 34.8 KB (dbuf)
    __shared__ __align__(16) ushort_t sP[2][16][PITCH];  // 8.7 KB (per wave)

    const int tid  = threadIdx.x;
    const int wave = tid >> 6;
    const int lane = tid & 63;
    const int li   = lane & 15;        // query index i (within 16-block)
    const int g    = lane >> 4;        // k-group 0..3
    const int b    = blockIdx.x >> 6;
    const int rb   = blockIdx.x & 63;
    const int i    = rb*32 + wave*16 + li;   // global query row

    const ushort_t* Kbase = Kg + (size_t)b * NN * 16;
    const ushort_t* Vbase = Vg + (size_t)b * NC * NN;

    // Q B-fragment (fixed): B[k][i] = Q[i][k]; k-slot blocks [qh,ql,qh,ql]
    const bf16x8 qfrag = *(const bf16x8*)(Qg + ((size_t)b*NN + i)*16 + (g & 1)*8);

    // staging assignments (128 threads)
    const int kst_row = tid;            // K tile row 0..127 (32B each)
    const int vst_c   = tid >> 1;       // V tile row 0..63
    const int vst_j   = (tid & 1) * 64; // which 64-j half (128B each)

    bf16x8 kr0, kr1, vr0, vr1, vr2, vr3, vr4, vr5, vr6, vr7;

    float m = -INFINITY, l = 0.f;
    f32x4 acc[4];
    #pragma unroll
    for (int cb = 0; cb < 4; cb++) acc[cb] = (f32x4){0.f,0.f,0.f,0.f};
    const f32x4 zero4 = {0.f,0.f,0.f,0.f};

    // ---- prologue: stage tile 0 ----
    {
        const ushort_t* kp = Kbase + (size_t)kst_row * 16;
        kr0 = *(const bf16x8*)kp;  kr1 = *(const bf16x8*)(kp + 8);
        const ushort_t* vp = Vbase + (size_t)vst_c * NN + vst_j;
        vr0 = *(const bf16x8*)(vp+ 0); vr1 = *(const bf16x8*)(vp+ 8);
        vr2 = *(const bf16x8*)(vp+16); vr3 = *(const bf16x8*)(vp+24);
        vr4 = *(const bf16x8*)(vp+32); vr5 = *(const bf16x8*)(vp+40);
        vr6 = *(const bf16x8*)(vp+48); vr7 = *(const bf16x8*)(vp+56);
        *(bf16x8*)&sK[0][kst_row][0] = kr0; *(bf16x8*)&sK[0][kst_row][8] = kr1;
        ushort_t* vd = &sV[0][vst_c][vst_j];
        *(bf16x8*)(vd+ 0)=vr0; *(bf16x8*)(vd+ 8)=vr1;
        *(bf16x8*)(vd+16)=vr2; *(bf16x8*)(vd+24)=vr3;
        *(bf16x8*)(vd+32)=vr4; *(bf16x8*)(vd+40)=vr5;
        *(bf16x8*)(vd+48)=vr6; *(bf16x8*)(vd+56)=vr7;
    }
    __syncthreads();

    int cur = 0;
    for (int t = 0; t < NT; t++) {
        // issue next tile's global loads early (hide under compute)
        if (t + 1 < NT) {
            const int j0 = (t + 1) * JT;
            const ushort_t* kp = Kbase + (size_t)(j0 + kst_row) * 16;
            kr0 = *(const bf16x8*)kp;  kr1 = *(const bf16x8*)(kp + 8);
            const ushort_t* vp = Vbase + (size_t)vst_c * NN + j0 + vst_j;
            vr0 = *(const bf16x8*)(vp+ 0); vr1 = *(const bf16x8*)(vp+ 8);
            vr2 = *(const bf16x8*)(vp+16); vr3 = *(const bf16x8*)(vp+24);
            vr4 = *(const bf16x8*)(vp+32); vr5 = *(const bf16x8*)(vp+40);
            vr6 = *(const bf16x8*)(vp+48); vr7 = *(const bf16x8*)(vp+56);
        }

        // ---- energies: E^T frag = mfma(A=K[hi,hi,lo,lo], B=Q[hi,lo,hi,lo]) ----
        // exact fp32 dot: (kh+kl)·(qh+ql), all 4 cross terms in one MFMA
        f32x4 e[8];
        #pragma unroll
        for (int f = 0; f < 8; f++) {
            bf16x8 kf = *(const bf16x8*)&sK[cur][f*16 + li][(g >> 1) * 8];
            e[f] = __builtin_amdgcn_mfma_f32_16x16x32_bf16(kf, qfrag, zero4, 0, 0, 0);
        }
        // lane holds E[i=li][j = f*16 + g*4 + q] -> row-local softmax
        float mx = -INFINITY;
        #pragma unroll
        for (int f = 0; f < 8; f++)
            mx = fmaxf(mx, fmaxf(fmaxf(e[f][0], e[f][1]), fmaxf(e[f][2], e[f][3])));
        mx = fmaxf(mx, __shfl_xor(mx, 16));
        mx = fmaxf(mx, __shfl_xor(mx, 32));
        const float newm = fmaxf(m, mx);
        const float scale = __expf(m - newm);   // 0 on first tile
        m = newm;
        l *= scale;
        #pragma unroll
        for (int cb = 0; cb < 4; cb++) {
            acc[cb][0] *= scale; acc[cb][1] *= scale;
            acc[cb][2] *= scale; acc[cb][3] *= scale;
        }
        float lsum = 0.f;
        #pragma unroll
        for (int f = 0; f < 8; f++) {
            float p0 = __expf(e[f][0] - m), p1 = __expf(e[f][1] - m);
            float p2 = __expf(e[f][2] - m), p3 = __expf(e[f][3] - m);
            lsum += (p0 + p1) + (p2 + p3);
            unsigned d0 = ((unsigned)f2bf(p1) << 16) | f2bf(p0);
            unsigned d1 = ((unsigned)f2bf(p3) << 16) | f2bf(p2);
            *(unsigned long long*)&sP[wave][li][f*16 + g*4] =
                (((unsigned long long)d1) << 32) | d0;
        }
        lsum += __shfl_xor(lsum, 16);
        lsum += __shfl_xor(lsum, 32);
        l += lsum;

        // ---- PV: acc[c][i] += sum_j V[c][j] P[i][j] = mfma(A=V, B=P) ----
        #pragma unroll
        for (int jc = 0; jc < 4; jc++) {
            bf16x8 pf = *(const bf16x8*)&sP[wave][li][jc*32 + g*8];
            #pragma unroll
            for (int cb = 0; cb < 4; cb++) {
                bf16x8 vf = *(const bf16x8*)&sV[cur][cb*16 + li][jc*32 + g*8];
                acc[cb] = __builtin_amdgcn_mfma_f32_16x16x32_bf16(vf, pf, acc[cb], 0, 0, 0);
            }
        }

        // write next tile into the other buffer (no one reads it until the
        // barrier below), then flip
        if (t + 1 < NT) {
            *(bf16x8*)&sK[cur^1][kst_row][0] = kr0;
            *(bf16x8*)&sK[cur^1][kst_row][8] = kr1;
            ushort_t* vd = &sV[cur^1][vst_c][vst_j];
            *(bf16x8*)(vd+ 0)=vr0; *(bf16x8*)(vd+ 8)=vr1;
            *(bf16x8*)(vd+16)=vr2; *(bf16x8*)(vd+24)=vr3;
            *(bf16x8*)(vd+32)=vr4; *(bf16x8*)(vd+40)=vr5;
            *(bf16x8*)(vd+48)=vr6; *(bf16x8*)(vd+56)=vr7;
        }
        __syncthreads();
        cur ^= 1;
    }

    // ---- epilogue: normalize, gamma, residual ----
    const float inv = 1.0f / l;
    const float gm  = gamma[0];
    const size_t base = (size_t)b * NC * NN + i;
    #pragma unroll
    for (int cb = 0; cb < 4; cb++) {
        #pragma unroll
        for (int qq = 0; qq < 4; qq++) {
            const size_t idx = base + (size_t)(cb*16 + g*4 + qq) * NN;
            out[idx] = fmaf(gm, acc[cb][qq] * inv, x[idx]);
        }
    }
}

extern "C" void kernel_launch(void* const* d_in, const int* in_sizes, int n_in,
                              void* d_out, int out_size, void* d_ws, size_t ws_size,
                              hipStream_t stream) {
    const float* x     = (const float*)d_in[0];
    const float* Wq    = (const float*)d_in[1];
    const float* bq    = (const float*)d_in[2];
    const float* Wk    = (const float*)d_in[3];
    const float* bk    = (const float*)d_in[4];
    const float* Wv    = (const float*)d_in[5];
    const float* bv    = (const float*)d_in[6];
    const float* gamma = (const float*)d_in[7];
    float* out = (float*)d_out;

    // workspace (ushorts): Q [8][2048][16], K [8][2048][16], V [8][64][2048] = 3 MB
    ushort_t* Qws = (ushort_t*)d_ws;
    ushort_t* Kws = Qws + (size_t)NB * NN * 16;   // +262144
    ushort_t* Vws = Kws + (size_t)NB * NN * 16;   // +262144

    qkv_kernel<<<(NB * NN) / 64, 64, 0, stream>>>(
        x, Wq, bq, Wk, bk, Wv, bv, Qws, Kws, Vws);
    attn_kernel<<<NB * (NN / 32), 128, 0, stream>>>(
        Qws, Kws, Vws, x, gamma, out);
}

// Round 3
// 42.961 us; speedup vs baseline: 5.1550x; 1.3918x over previous
//
#include <hip/hip_runtime.h>
#include <math.h>

// PAM module: B=8, C=64, CQ=8, N=2048
// out[b,c,i] = gamma * sum_j softmax_j(q[i,:]·k[:,j]) * v[c,j] + x[b,c,i]

#define NB  8
#define NC  64
#define NCQ 8
#define NN  2048
#define JT2 64           // j-tile per step (per half)
#define NT2 16           // steps per half (1024/64)
#define VP  72           // V/P LDS pitch in ushorts (144B rows: 16B-aligned, 2-way max)
#define L2E 1.44269504088896340736f

typedef float f32x4 __attribute__((ext_vector_type(4)));
typedef __bf16 bf16x8 __attribute__((ext_vector_type(8)));
typedef __bf16 bf16x4 __attribute__((ext_vector_type(4)));
typedef unsigned short ushort_t;
typedef unsigned short us8 __attribute__((ext_vector_type(8)));

__device__ __forceinline__ unsigned short f2bf(float f) {
    unsigned u = __float_as_uint(f);
    u += 0x7fffu + ((u >> 16) & 1u);          // RNE
    return (unsigned short)(u >> 16);
}
__device__ __forceinline__ float bf2f(unsigned short h) {
    return __uint_as_float(((unsigned)h) << 16);
}

// ---------------- prep: transpose weights into ws ----------------
// WT[c][80] with o: 0..7 = Wq-row-o (prescaled by log2e), 8..15 = Wk, 16..79 = Wv
// ball[80] biases in the same order (bq prescaled).
__global__ void prep_kernel(const float* __restrict__ Wq, const float* __restrict__ bq,
                            const float* __restrict__ Wk, const float* __restrict__ bk,
                            const float* __restrict__ Wv, const float* __restrict__ bv,
                            float* __restrict__ wsf)
{
    const int gid = blockIdx.x * 256 + threadIdx.x;
    if (gid < 5120) {
        const int c = gid / 80;
        const int o = gid - c * 80;
        float v;
        if (o < 8)       v = Wq[o * NC + c] * L2E;
        else if (o < 16) v = Wk[(o - 8) * NC + c];
        else             v = Wv[(o - 16) * NC + c];
        wsf[gid] = v;
    }
    if (gid < 80) {
        float v;
        if (gid < 8)       v = bq[gid] * L2E;
        else if (gid < 16) v = bk[gid - 8];
        else               v = bv[gid - 16];
        wsf[5120 + gid] = v;
    }
}

// ---------------- QKV projection ----------------
// 256 blocks x 256 threads; block covers 64 pixels of one batch; the 4 waves
// split the 80 output channels (20 each). Weights via wave-uniform s_loads.
__global__ __launch_bounds__(256) void qkv_kernel(
    const float* __restrict__ x, const float* __restrict__ wsf,
    ushort_t* __restrict__ Qws, ushort_t* __restrict__ Kws,
    ushort_t* __restrict__ Vws)
{
    __shared__ float sX[64][68];     // [pixel][channel], pitch 68 (b128-friendly)
    const int tid = threadIdx.x;
    const int b  = blockIdx.x >> 5;
    const int n0 = (blockIdx.x & 31) * 64;
    const float* xg = x + (size_t)b * NC * NN + n0;

    for (int it = tid; it < 4096; it += 256) {
        const int c = it >> 6, nl = it & 63;
        sX[nl][c] = xg[(size_t)c * NN + nl];
    }
    __syncthreads();

    const int nl  = tid & 63;
    const int sgu = __builtin_amdgcn_readfirstlane(tid >> 6);
    const int base = sgu * 20;
    const float* WT   = wsf;
    const float* ball = wsf + 5120;

    float acc[20];
    #pragma unroll
    for (int j = 0; j < 20; j++) acc[j] = ball[base + j];

    #pragma unroll
    for (int c4 = 0; c4 < 16; c4++) {
        const f32x4 xv4 = *(const f32x4*)&sX[nl][c4 * 4];
        #pragma unroll
        for (int e = 0; e < 4; e++) {
            const float xv = xv4[e];
            const float* wp = WT + (c4 * 4 + e) * 80 + base;
            #pragma unroll
            for (int j4 = 0; j4 < 5; j4++) {
                const f32x4 wv = *(const f32x4*)(wp + j4 * 4);
                acc[j4*4+0] = fmaf(wv[0], xv, acc[j4*4+0]);
                acc[j4*4+1] = fmaf(wv[1], xv, acc[j4*4+1]);
                acc[j4*4+2] = fmaf(wv[2], xv, acc[j4*4+2]);
                acc[j4*4+3] = fmaf(wv[3], xv, acc[j4*4+3]);
            }
        }
    }

    const int n = n0 + nl;
    if (sgu == 0) {
        // q (log2e-prescaled) and k as [hi(8)|lo(8)] double-bf16 rows
        us8 qh8, ql8, kh8, kl8;
        #pragma unroll
        for (int o = 0; o < 8; o++) {
            const unsigned short qh = f2bf(acc[o]);
            qh8[o] = qh; ql8[o] = f2bf(acc[o] - bf2f(qh));
            const unsigned short kh = f2bf(acc[8 + o]);
            kh8[o] = kh; kl8[o] = f2bf(acc[8 + o] - bf2f(kh));
        }
        ushort_t* qo = Qws + ((size_t)b * NN + n) * 16;
        ushort_t* ko = Kws + ((size_t)b * NN + n) * 16;
        *(us8*)qo = qh8; *(us8*)(qo + 8) = ql8;
        *(us8*)ko = kh8; *(us8*)(ko + 8) = kl8;
        #pragma unroll
        for (int j = 0; j < 4; j++)
            Vws[((size_t)b * NC + j) * NN + n] = f2bf(acc[16 + j]);
    } else {
        #pragma unroll
        for (int j = 0; j < 20; j++) {
            const int c = base - 16 + j;
            Vws[((size_t)b * NC + c) * NN + n] = f2bf(acc[j]);
        }
    }
}

// ---------------- fused flash attention (MFMA, split-j) ----------------
// 512 threads = 8 waves = 4 row-groups x 2 j-halves; 64 query rows per block.
// grid = 8 * 32 = 256 blocks. K fragments direct from global (prefetched);
// V double-buffered in LDS; softmax in exp2 domain (Q pre-scaled by log2e).
__global__ __launch_bounds__(512) void attn_kernel(
    const ushort_t* __restrict__ Qg, const ushort_t* __restrict__ Kg,
    const ushort_t* __restrict__ Vg, const float* __restrict__ x,
    const float* __restrict__ gamma, float* __restrict__ out)
{
    __shared__ __align__(16) ushort_t sV[2][2][NC][VP];  // 36.9 KB (dbuf x half)
    __shared__ __align__(16) ushort_t sP[8][16][VP];     // 18.4 KB (per wave)

    const int tid  = threadIdx.x;
    const int w    = tid >> 6;          // wave 0..7
    const int rg   = w & 3;             // row-group
    const int jh   = w >> 2;            // j-half
    const int lane = tid & 63;
    const int li   = lane & 15;
    const int g    = lane >> 4;
    const int b    = blockIdx.x >> 5;
    const int rb   = blockIdx.x & 31;
    const int i    = rb * 64 + rg * 16 + li;    // global query row

    const ushort_t* Kb = Kg + (size_t)b * NN * 16;
    const ushort_t* Vb = Vg + (size_t)b * NC * NN;

    const bf16x8 qfrag = *(const bf16x8*)(Qg + ((size_t)b * NN + i) * 16 + (g & 1) * 8);

    // V staging map: 512 threads stage both halves' 64x64 tiles (32 B each)
    const int s_h = tid >> 8;
    const int s_u = tid & 255;
    const int s_c = s_u >> 2;
    const int s_j = (s_u & 3) * 8;
    const ushort_t* vsrc = Vb + (size_t)s_c * NN + s_h * 1024 + s_j;

    const int jbase = jh * 1024;

    // ---- prologue: stage V tile 0, prefetch K frags for step 0 ----
    {
        const bf16x8 a0 = *(const bf16x8*)(vsrc);
        const bf16x8 a1 = *(const bf16x8*)(vsrc + 32);
        *(bf16x8*)&sV[0][s_h][s_c][s_j]      = a0;
        *(bf16x8*)&sV[0][s_h][s_c][s_j + 32] = a1;
    }
    bf16x8 kc[4];
    #pragma unroll
    for (int f = 0; f < 4; f++)
        kc[f] = *(const bf16x8*)(Kb + (size_t)(jbase + f * 16 + li) * 16 + (g >> 1) * 8);
    __syncthreads();

    float m = -INFINITY, l = 0.f;
    f32x4 acc[4];
    #pragma unroll
    for (int cb = 0; cb < 4; cb++) acc[cb] = (f32x4){0.f, 0.f, 0.f, 0.f};
    const f32x4 zero4 = {0.f, 0.f, 0.f, 0.f};

    int cur = 0;
    for (int t = 0; t < NT2; t++) {
        // issue next step's loads early (hide latency under compute)
        bf16x8 kn[4], v0n, v1n;
        const bool more = (t + 1) < NT2;
        if (more) {
            const int j0n = jbase + (t + 1) * JT2;
            #pragma unroll
            for (int f = 0; f < 4; f++)
                kn[f] = *(const bf16x8*)(Kb + (size_t)(j0n + f * 16 + li) * 16 + (g >> 1) * 8);
            v0n = *(const bf16x8*)(vsrc + (t + 1) * JT2);
            v1n = *(const bf16x8*)(vsrc + (t + 1) * JT2 + 32);
        }

        // ---- energies (exp2-domain): exact fp32 dot via hi/lo cross terms ----
        f32x4 e[4];
        __builtin_amdgcn_s_setprio(1);
        #pragma unroll
        for (int f = 0; f < 4; f++)
            e[f] = __builtin_amdgcn_mfma_f32_16x16x32_bf16(kc[f], qfrag, zero4, 0, 0, 0);
        __builtin_amdgcn_s_setprio(0);

        float mx = -INFINITY;
        #pragma unroll
        for (int f = 0; f < 4; f++)
            mx = fmaxf(mx, fmaxf(fmaxf(e[f][0], e[f][1]), fmaxf(e[f][2], e[f][3])));
        mx = fmaxf(mx, __shfl_xor(mx, 16));
        mx = fmaxf(mx, __shfl_xor(mx, 32));
        const float nm = fmaxf(m, mx);
        const float sc = __builtin_amdgcn_exp2f(m - nm);   // 0 on first step
        m = nm;
        l *= sc;
        #pragma unroll
        for (int cb = 0; cb < 4; cb++) {
            acc[cb][0] *= sc; acc[cb][1] *= sc;
            acc[cb][2] *= sc; acc[cb][3] *= sc;
        }
        float ls = 0.f;
        #pragma unroll
        for (int f = 0; f < 4; f++) {
            const float p0 = __builtin_amdgcn_exp2f(e[f][0] - m);
            const float p1 = __builtin_amdgcn_exp2f(e[f][1] - m);
            const float p2 = __builtin_amdgcn_exp2f(e[f][2] - m);
            const float p3 = __builtin_amdgcn_exp2f(e[f][3] - m);
            ls += (p0 + p1) + (p2 + p3);
            const bf16x4 pk = { (__bf16)p0, (__bf16)p1, (__bf16)p2, (__bf16)p3 };
            *(bf16x4*)&sP[w][li][f * 16 + g * 4] = pk;
        }
        ls += __shfl_xor(ls, 16);
        ls += __shfl_xor(ls, 32);
        l += ls;

        // ---- PV ----
        __builtin_amdgcn_s_setprio(1);
        #pragma unroll
        for (int jc = 0; jc < 2; jc++) {
            const bf16x8 pf = *(const bf16x8*)&sP[w][li][jc * 32 + g * 8];
            #pragma unroll
            for (int cb = 0; cb < 4; cb++) {
                const bf16x8 vf = *(const bf16x8*)&sV[cur][jh][cb * 16 + li][jc * 32 + g * 8];
                acc[cb] = __builtin_amdgcn_mfma_f32_16x16x32_bf16(vf, pf, acc[cb], 0, 0, 0);
            }
        }
        __builtin_amdgcn_s_setprio(0);

        // write next V tile (other buffer), keep prefetched K
        if (more) {
            *(bf16x8*)&sV[cur ^ 1][s_h][s_c][s_j]      = v0n;
            *(bf16x8*)&sV[cur ^ 1][s_h][s_c][s_j + 32] = v1n;
            #pragma unroll
            for (int f = 0; f < 4; f++) kc[f] = kn[f];
        }
        __syncthreads();
        cur ^= 1;
    }

    // ---- merge the two j-halves (alias sP as float scratch) ----
    float* sM = (float*)&sP[0][0][0];
    float* mp = sM + ((size_t)rg * 64 + lane) * 18;
    if (jh == 1) {
        #pragma unroll
        for (int cb = 0; cb < 4; cb++) {
            mp[cb*4+0] = acc[cb][0]; mp[cb*4+1] = acc[cb][1];
            mp[cb*4+2] = acc[cb][2]; mp[cb*4+3] = acc[cb][3];
        }
        mp[16] = m; mp[17] = l;
    }
    __syncthreads();
    if (jh == 0) {
        const float m1 = mp[16], l1 = mp[17];
        const float ms = fmaxf(m, m1);
        const float s0 = __builtin_amdgcn_exp2f(m - ms);
        const float s1 = __builtin_amdgcn_exp2f(m1 - ms);
        const float inv = 1.0f / (l * s0 + l1 * s1);
        const float gmv = gamma[0];
        const size_t base = (size_t)b * NC * NN + i;
        #pragma unroll
        for (int cb = 0; cb < 4; cb++) {
            #pragma unroll
            for (int q = 0; q < 4; q++) {
                const float a = (acc[cb][q] * s0 + mp[cb*4+q] * s1) * inv;
                const size_t idx = base + (size_t)(cb * 16 + g * 4 + q) * NN;
                out[idx] = fmaf(gmv, a, x[idx]);
            }
        }
    }
}

extern "C" void kernel_launch(void* const* d_in, const int* in_sizes, int n_in,
                              void* d_out, int out_size, void* d_ws, size_t ws_size,
                              hipStream_t stream) {
    const float* x     = (const float*)d_in[0];
    const float* Wq    = (const float*)d_in[1];
    const float* bq    = (const float*)d_in[2];
    const float* Wk    = (const float*)d_in[3];
    const float* bk    = (const float*)d_in[4];
    const float* Wv    = (const float*)d_in[5];
    const float* bv    = (const float*)d_in[6];
    const float* gamma = (const float*)d_in[7];
    float* out = (float*)d_out;

    // ws layout: Qws 512KB | Kws 512KB | Vws 2MB | float WT(5120)+ball(80)
    ushort_t* Qws = (ushort_t*)d_ws;
    ushort_t* Kws = Qws + (size_t)NB * NN * 16;
    ushort_t* Vws = Kws + (size_t)NB * NN * 16;
    float*    wsf = (float*)((char*)d_ws + 3145728);

    prep_kernel<<<20, 256, 0, stream>>>(Wq, bq, Wk, bk, Wv, bv, wsf);
    qkv_kernel<<<256, 256, 0, stream>>>(x, wsf, Qws, Kws, Vws);
    attn_kernel<<<NB * 32, 512, 0, stream>>>(Qws, Kws, Vws, x, gamma, out);
}